// Round 1
// baseline (78.210 us; speedup 1.0000x reference)
//
#include <hip/hip_runtime.h>
#include <math.h>

#define BSZ 4096
#define NTOK 8192
// total elements = 4096*8192 = 2^25 (fits int)
#define NVEC (BSZ * NTOK / 4)

#define NBLOCKS 2048
#define NTHREADS 256

__global__ __launch_bounds__(NTHREADS) void gauss_nll_partial(
    const float4* __restrict__ mu,
    const float4* __restrict__ sigma,
    const float4* __restrict__ ty,
    float* __restrict__ partials) {
    int tid = blockIdx.x * NTHREADS + threadIdx.x;
    const int stride = NBLOCKS * NTHREADS;

    float acc = 0.0f;
    for (int i = tid; i < NVEC; i += stride) {
        float4 m = mu[i];
        float4 s = sigma[i];
        float4 t = ty[i];
        float d0 = t.x - m.x;
        float d1 = t.y - m.y;
        float d2 = t.z - m.z;
        float d3 = t.w - m.w;
        acc += __logf(s.x) + d0 * d0 * __frcp_rn(s.x);
        acc += __logf(s.y) + d1 * d1 * __frcp_rn(s.y);
        acc += __logf(s.z) + d2 * d2 * __frcp_rn(s.z);
        acc += __logf(s.w) + d3 * d3 * __frcp_rn(s.w);
    }

    // wave-64 butterfly reduce
    for (int off = 32; off > 0; off >>= 1)
        acc += __shfl_down(acc, off, 64);

    __shared__ float wsum[NTHREADS / 64];
    int lane = threadIdx.x & 63;
    int wid = threadIdx.x >> 6;
    if (lane == 0) wsum[wid] = acc;
    __syncthreads();
    if (threadIdx.x == 0) {
        float b = wsum[0] + wsum[1] + wsum[2] + wsum[3];
        partials[blockIdx.x] = b;
    }
}

__global__ __launch_bounds__(256) void gauss_nll_final(
    const float* __restrict__ partials, float* __restrict__ out) {
    float acc = 0.0f;
    for (int i = threadIdx.x; i < NBLOCKS; i += 256)
        acc += partials[i];
    for (int off = 32; off > 0; off >>= 1)
        acc += __shfl_down(acc, off, 64);
    __shared__ float wsum[4];
    int lane = threadIdx.x & 63;
    int wid = threadIdx.x >> 6;
    if (lane == 0) wsum[wid] = acc;
    __syncthreads();
    if (threadIdx.x == 0) {
        float total = wsum[0] + wsum[1] + wsum[2] + wsum[3];
        const float log2pi = 1.8378770664093453f;  // log(2*pi)
        out[0] = 0.5f * ((float)NTOK * log2pi + total / (float)BSZ);
    }
}

extern "C" void kernel_launch(void* const* d_in, const int* in_sizes, int n_in,
                              void* d_out, int out_size, void* d_ws, size_t ws_size,
                              hipStream_t stream) {
    const float4* mu = (const float4*)d_in[0];
    const float4* sigma = (const float4*)d_in[1];
    const float4* ty = (const float4*)d_in[2];
    float* out = (float*)d_out;
    float* partials = (float*)d_ws;  // NBLOCKS floats, fully written each call

    gauss_nll_partial<<<NBLOCKS, NTHREADS, 0, stream>>>(mu, sigma, ty, partials);
    gauss_nll_final<<<1, 256, 0, stream>>>(partials, out);
}

// Round 2
// 76.737 us; speedup vs baseline: 1.0192x; 1.0192x over previous
//
#include <hip/hip_runtime.h>
#include <math.h>

#define BSZ 4096
#define NTOK 8192
// total elements = 4096*8192 = 2^25
#define NVEC (BSZ * NTOK / 4)

#define NBLOCKS 2048
#define NTHREADS 256
#define STRIDE (NBLOCKS * NTHREADS)  // 524288; NVEC = 16*STRIDE exactly

__device__ __forceinline__ float elem4(float4 m, float4 s, float4 t) {
    float d0 = t.x - m.x;
    float d1 = t.y - m.y;
    float d2 = t.z - m.z;
    float d3 = t.w - m.w;
    float r = 0.0f;
    r += __logf(s.x) + d0 * d0 * __builtin_amdgcn_rcpf(s.x);
    r += __logf(s.y) + d1 * d1 * __builtin_amdgcn_rcpf(s.y);
    r += __logf(s.z) + d2 * d2 * __builtin_amdgcn_rcpf(s.z);
    r += __logf(s.w) + d3 * d3 * __builtin_amdgcn_rcpf(s.w);
    return r;
}

__global__ __launch_bounds__(NTHREADS) void gauss_nll_partial(
    const float4* __restrict__ mu,
    const float4* __restrict__ sigma,
    const float4* __restrict__ ty,
    float* __restrict__ partials) {
    int tid = blockIdx.x * NTHREADS + threadIdx.x;

    float acc0 = 0.0f, acc1 = 0.0f;
    // 8 outer iterations, 2x unrolled: 6 independent 16B loads in flight,
    // two accumulator chains.
    for (int i = tid; i < NVEC; i += 2 * STRIDE) {
        float4 m0 = mu[i];
        float4 m1 = mu[i + STRIDE];
        float4 s0 = sigma[i];
        float4 s1 = sigma[i + STRIDE];
        float4 t0 = ty[i];
        float4 t1 = ty[i + STRIDE];
        acc0 += elem4(m0, s0, t0);
        acc1 += elem4(m1, s1, t1);
    }
    float acc = acc0 + acc1;

    // wave-64 butterfly reduce
    for (int off = 32; off > 0; off >>= 1)
        acc += __shfl_down(acc, off, 64);

    __shared__ float wsum[NTHREADS / 64];
    int lane = threadIdx.x & 63;
    int wid = threadIdx.x >> 6;
    if (lane == 0) wsum[wid] = acc;
    __syncthreads();
    if (threadIdx.x == 0) {
        partials[blockIdx.x] = wsum[0] + wsum[1] + wsum[2] + wsum[3];
    }
}

__global__ __launch_bounds__(256) void gauss_nll_final(
    const float* __restrict__ partials, float* __restrict__ out) {
    float acc = 0.0f;
    for (int i = threadIdx.x; i < NBLOCKS; i += 256)
        acc += partials[i];
    for (int off = 32; off > 0; off >>= 1)
        acc += __shfl_down(acc, off, 64);
    __shared__ float wsum[4];
    int lane = threadIdx.x & 63;
    int wid = threadIdx.x >> 6;
    if (lane == 0) wsum[wid] = acc;
    __syncthreads();
    if (threadIdx.x == 0) {
        float total = wsum[0] + wsum[1] + wsum[2] + wsum[3];
        const float log2pi = 1.8378770664093453f;  // log(2*pi)
        out[0] = 0.5f * ((float)NTOK * log2pi + total / (float)BSZ);
    }
}

extern "C" void kernel_launch(void* const* d_in, const int* in_sizes, int n_in,
                              void* d_out, int out_size, void* d_ws, size_t ws_size,
                              hipStream_t stream) {
    const float4* mu = (const float4*)d_in[0];
    const float4* sigma = (const float4*)d_in[1];
    const float4* ty = (const float4*)d_in[2];
    float* out = (float*)d_out;
    float* partials = (float*)d_ws;  // NBLOCKS floats, fully written each call

    gauss_nll_partial<<<NBLOCKS, NTHREADS, 0, stream>>>(mu, sigma, ty, partials);
    gauss_nll_final<<<1, 256, 0, stream>>>(partials, out);
}